// Round 6
// baseline (252.732 us; speedup 1.0000x reference)
//
#include <hip/hip_runtime.h>

typedef unsigned long long u64;
typedef unsigned int u32;

#define R_TOT 159882
#define POST 1000
#define IMG_SZ 800.0f
#define NMS_TH 0.7f
#define BBOX_CLIP 4.135166556742356f
#define LCAP 2048

__device__ __forceinline__ float fadd_(float a, float b){ return __fadd_rn(a,b); }
__device__ __forceinline__ float fsub_(float a, float b){ return __fsub_rn(a,b); }
__device__ __forceinline__ float fmul_(float a, float b){ return __fmul_rn(a,b); }

__device__ __forceinline__ int lvl_len(int l){ const int L[5]={120000,30000,7500,1875,507}; return L[l]; }
__device__ __forceinline__ int lvl_off(int l){ const int L[5]={0,120000,150000,157500,159375}; return L[l]; }
__device__ __forceinline__ int lvl_k(int l){ const int L[5]={1000,1000,1000,1000,507}; return L[l]; }

__device__ __forceinline__ u32 mono_(u32 u){ return (u & 0x80000000u) ? ~u : (u | 0x80000000u); }

// ---------- 1. 12-bit histogram per (img,lvl): LDS-private, merged once ----------
__global__ __launch_bounds__(256) void k_hist(const float* __restrict__ obj, int* hist){
  int g = blockIdx.x, sl = blockIdx.y;
  int img = g/5, lvl = g%5;
  int n = lvl_len(lvl), s0 = lvl_off(lvl);
  __shared__ int lh[4096];
  int tid = threadIdx.x;
  for (int i = tid; i < 4096; i += 256) lh[i] = 0;
  __syncthreads();
  int lo = (int)((long long)n * sl / 16), hiS = (int)((long long)n * (sl+1) / 16);
  const float* p = obj + img*R_TOT + s0;
  #pragma unroll 4
  for (int e = lo + tid; e < hiS; e += 256){
    u32 mu = mono_(__float_as_uint(p[e]));
    atomicAdd(&lh[(~mu) >> 20], 1);
  }
  __syncthreads();
  for (int i = tid; i < 4096; i += 256)
    if (lh[i]) atomicAdd(&hist[g*4096 + i], lh[i]);
}

// ---------- 2. fused: pick bin + gather + rank-resolve + sort + decode + prep ----------
__global__ __launch_bounds__(1024) void k_sel(const float* __restrict__ obj,
                                              const float4* __restrict__ deltas,
                                              const float4* __restrict__ anchors,
                                              const int* __restrict__ hist,
                                              float4* boxL, float* scoreL, u64* okeyL,
                                              float4* nbox, int* nrank, int* ncnt){
  int g = blockIdx.x, img = g/5, lvl = g%5;
  int s0 = lvl_off(lvl), n = lvl_len(lvl), k = lvl_k(lvl);
  const float* p = obj + img*R_TOT + s0;
  __shared__ u64 Lbuf[LCAP];
  __shared__ u64 mainL[1024];
  __shared__ float4 lbox[1024];
  __shared__ unsigned char lval[1024];
  __shared__ int wsum[16];
  __shared__ int h16[16];
  __shared__ int sh_b, sh_rem, sh_nb, sh_c2, sh_sc;
  __shared__ u64 sh_thr;
  int tid = threadIdx.x, lane = tid & 63, wid = tid >> 6;
  // --- pick k-th bin from global hist ---
  const int* hg = hist + g*4096;
  int hh[4] = {hg[4*tid], hg[4*tid+1], hg[4*tid+2], hg[4*tid+3]};
  int part = hh[0] + hh[1] + hh[2] + hh[3];
  int x = part;
  for (int d = 1; d < 64; d <<= 1){ int y = __shfl_up(x, d); if (lane >= d) x += y; }
  if (lane == 63) wsum[wid] = x;
  if (tid == 0){ sh_nb = 0; sh_c2 = 0; sh_sc = 0; }
  mainL[tid] = ~0ull;
  __syncthreads();
  int add = 0;
  for (int w = 0; w < wid; w++) add += wsum[w];
  int incl = x + add, excl = incl - part;
  if (excl < k && k <= incl){
    int cum = excl;
    #pragma unroll
    for (int q = 0; q < 4; q++){
      if (cum + hh[q] >= k){ sh_b = 4*tid + q; sh_rem = k - cum; break; }
      cum += hh[q];
    }
  }
  __syncthreads();
  int bs = sh_b, rem = sh_rem;
  // --- single collect scan: bin<b* -> mainL, bin==b* -> Lbuf ---
  #pragma unroll 8
  for (int e = tid; e < n; e += 1024){
    u32 mu = mono_(__float_as_uint(p[e]));
    u64 key56 = (((u64)(~mu)) << 24) | (u32)(s0 + e);
    int bin = (int)(key56 >> 44);
    if (bin < bs){ int pos = atomicAdd(&sh_nb, 1); mainL[pos] = key56; }
    else if (bin == bs){ int pos = atomicAdd(&sh_c2, 1); if (pos < LCAP) Lbuf[pos] = key56; }
  }
  __syncthreads();
  int nb = sh_nb, c2 = sh_c2;
  if (c2 <= LCAP){
    // rank-select within the tie bin (uniform q -> LDS broadcast)
    for (int e = tid; e < c2; e += 1024){
      u64 kk = Lbuf[e];
      int rk = 0;
      for (int q = 0; q < c2; q++) rk += (Lbuf[q] < kk) ? 1 : 0;
      if (rk < rem){ int p2 = atomicAdd(&sh_sc, 1); mainL[nb + p2] = kk; }
    }
  } else {
    // fallback: 4-bit radix refine over global (never hit on bench data)
    if (tid == 0) sh_thr = ((u64)bs) << 44;
    __syncthreads();
    for (int shift = 40; shift >= 0; shift -= 4){
      if (tid < 16) h16[tid] = 0;
      __syncthreads();
      u64 pref = sh_thr;
      u64 himask = ~((1ull << (shift+4)) - 1ull);
      for (int e = tid; e < n; e += 1024){
        u32 mu = mono_(__float_as_uint(p[e]));
        u64 kk = (((u64)(~mu)) << 24) | (u32)(s0 + e);
        if ((kk & himask) == (pref & himask)) atomicAdd(&h16[(int)((kk >> shift) & 15)], 1);
      }
      __syncthreads();
      if (tid == 0){
        int r2 = sh_rem, cum = 0;
        for (int d = 0; d < 16; d++){
          int hb = h16[d];
          if (cum + hb >= r2){ sh_thr = pref | ((u64)d << shift); sh_rem = r2 - cum; break; }
          cum += hb;
        }
      }
      __syncthreads();
    }
    u64 thr = sh_thr;
    for (int e = tid; e < n; e += 1024){
      u32 mu = mono_(__float_as_uint(p[e]));
      u64 kk = (((u64)(~mu)) << 24) | (u32)(s0 + e);
      if ((int)(kk >> 44) == bs && kk <= thr){ int p2 = atomicAdd(&sh_sc, 1); mainL[nb + p2] = kk; }
    }
  }
  __syncthreads();
  // --- bitonic sort 1024 (55 stages) ---
  for (int k2 = 2; k2 <= 1024; k2 <<= 1){
    for (int j = k2 >> 1; j > 0; j >>= 1){
      __syncthreads();
      int i = tid, ixj = i ^ j;
      if (ixj > i){
        u64 a = mainL[i], b = mainL[ixj];
        bool up = (i & k2) == 0;
        if ((a > b) == up){ mainL[i] = b; mainL[ixj] = a; }
      }
    }
  }
  __syncthreads();
  // --- decode + clip + valid + sigmoid + okey ---
  int r = tid, t = g*1024 + r;
  if (r < k){
    int idx = (int)(mainL[r] & 0xFFFFFFu);
    float4 a = anchors[idx];
    float4 d = deltas[img*R_TOT + idx];
    float o = obj[img*R_TOT + idx];
    float wa = fsub_(a.z, a.x), ha = fsub_(a.w, a.y);
    float cxa = fadd_(a.x, fmul_(0.5f, wa)), cya = fadd_(a.y, fmul_(0.5f, ha));
    float dw = fminf(d.z, BBOX_CLIP), dh = fminf(d.w, BBOX_CLIP);
    float cx = fadd_(fmul_(d.x, wa), cxa), cy = fadd_(fmul_(d.y, ha), cya);
    float w  = fmul_(expf(dw), wa),        h  = fmul_(expf(dh), ha);
    float x1 = fsub_(cx, fmul_(0.5f, w)), y1 = fsub_(cy, fmul_(0.5f, h));
    float x2 = fadd_(cx, fmul_(0.5f, w)), y2 = fadd_(cy, fmul_(0.5f, h));
    x1 = fminf(fmaxf(x1, 0.0f), IMG_SZ); y1 = fminf(fmaxf(y1, 0.0f), IMG_SZ);
    x2 = fminf(fmaxf(x2, 0.0f), IMG_SZ); y2 = fminf(fmaxf(y2, 0.0f), IMG_SZ);
    bool valid = (fsub_(x2, x1) >= 1e-3f) && (fsub_(y2, y1) >= 1e-3f);
    float e = expf(-o);
    float sig = __fdiv_rn(1.0f, fadd_(1.0f, e));
    float s = valid ? sig : -1.0f;
    u32 sb = __float_as_uint(s);
    u32 ms = (sb & 0x80000000u) ? ~sb : (sb | 0x80000000u);
    float4 b4 = make_float4(x1, y1, x2, y2);
    boxL[t] = b4;
    scoreL[t] = sig;
    okeyL[t] = (((u64)(~ms)) << 32) | (u32)(lvl*1000 + r);
    lbox[r] = b4;
    lval[r] = valid ? 1 : 0;
  } else {
    lval[r] = 0;
  }
  __syncthreads();
  // --- valid-compaction (wave 0) with 801*lvl offset ---
  if (tid < 64){
    int cnt = 0;
    float off = (float)lvl * 801.0f;
    for (int base = 0; base < k; base += 64){
      int r2 = base + lane;
      bool v = (r2 < k) && lval[r2];
      float4 b = lbox[r2 < k ? r2 : 0];
      u64 mask = __ballot(v);
      int before = __popcll(mask & ((1ull << lane) - 1ull));
      if (v){
        int pos = cnt + before;
        nbox[g*1024 + pos] = make_float4(fadd_(b.x,off), fadd_(b.y,off), fadd_(b.z,off), fadd_(b.w,off));
        nrank[g*1024 + pos] = r2;
      }
      cnt += __popcll(mask);
    }
    if (lane == 0) ncnt[g] = cnt;
  }
}

// ---------- 3. transposed IoU bitmask ----------
__global__ __launch_bounds__(64) void k_mask(const float4* __restrict__ nbox,
                                             const int* __restrict__ ncnt, u64* maskT){
  int g = blockIdx.x, tr = blockIdx.y, tw = blockIdx.z;
  if (tw > tr) return;
  int m = ncnt[g];
  if (tr*64 >= m) return;
  __shared__ float4 shb[64];
  int lane = threadIdx.x;
  if (tw*64 + lane < m) shb[lane] = nbox[g*1024 + tw*64 + lane];
  __syncthreads();
  int j = tr*64 + lane;
  if (j >= m) return;
  float4 a = nbox[g*1024 + j];
  float areaA = fmul_(fsub_(a.z,a.x), fsub_(a.w,a.y));
  int imax = m - tw*64; if (imax > 64) imax = 64;
  int cap = (tw == tr) ? (lane < imax ? lane : imax) : imax;   // strict i < j
  u64 bits = 0;
  for (int ii = 0; ii < cap; ii++){
    float4 b = shb[ii];
    float ltx = fmaxf(a.x, b.x), lty = fmaxf(a.y, b.y);
    float rbx = fminf(a.z, b.z), rby = fminf(a.w, b.w);
    float wx = fmaxf(fsub_(rbx, ltx), 0.0f), wy = fmaxf(fsub_(rby, lty), 0.0f);
    float inter = fmul_(wx, wy);
    float areaB = fmul_(fsub_(b.z,b.x), fsub_(b.w,b.y));
    float den = fadd_(fsub_(fadd_(areaA, areaB), inter), 1e-9f);
    if (__fdiv_rn(inter, den) > NMS_TH) bits |= (1ull << ii);
  }
  maskT[(size_t)(g*1024 + j)*16 + tw] = bits;
}

__device__ __forceinline__ int lbound(const u64* a, int n, u64 key){
  int lo = 0, hi = n;
  while (lo < hi){ int mid = (lo + hi) >> 1; if (a[mid] < key) lo = mid + 1; else hi = mid; }
  return lo;
}

// ---------- 4. fused greedy scan (waves 0-4) + 5-way merge by rank + output ----------
__global__ __launch_bounds__(1024) void k_scanmerge(const u64* __restrict__ maskT,
                                                    const int* __restrict__ ncnt,
                                                    const int* __restrict__ nrank,
                                                    const u64* __restrict__ okeyL,
                                                    const float4* __restrict__ boxL,
                                                    const float* __restrict__ scoreL,
                                                    float* out){
  int img = blockIdx.x, tid = threadIdx.x, lane = tid & 63, wid = tid >> 6;
  __shared__ unsigned char keptF[5*1024];
  __shared__ u64 runs[5*1024];
  __shared__ u64 Kw[5*16];
  __shared__ int cl[5];
  for (int i = tid; i < 5*1024; i += 1024) keptF[i] = 0;
  if (tid < 80) Kw[tid] = 0;
  if (tid < 5) cl[tid] = 0;
  __syncthreads();
  // --- per-level greedy scan, one wave each (wave-local LDS, no block barriers) ---
  // NOTE: no per-thread u64 array here — a runtime-indexed register array demotes
  // to scratch (R5: VGPR_Count=32 + 87us). Fully unrolled loads + cndmask select.
  if (wid < 5){
    int l = wid, g = img*5 + l;
    int m = ncnt[g];
    int nch = (m + 63) >> 6;
    for (int c = 0; c < nch; c++){
      int row = c*64 + lane;
      bool inr = row < m;
      const u64* rp = maskT + (size_t)(g*1024 + row)*16;
      u64 supp = 0, colbits = 0;
      #pragma unroll
      for (int q = 0; q < 16; q++){
        u64 v = inr ? rp[q] : 0;           // words q>c unwritten, but Kw[q]=0 masks them
        supp |= v & Kw[l*16 + q];
        colbits = (q == c) ? v : colbits;  // compile-time q -> v_cndmask, no scratch
      }
      int rnk = inr ? nrank[g*1024 + row] : 0;
      bool alive = inr && (supp == 0);
      u64 live = __ballot(alive);
      u64 kept = 0;
      while (live){
        int i = __builtin_ctzll(live);
        kept |= (1ull << i);
        if ((colbits >> i) & 1ull) alive = false;
        u64 below = (1ull << i) | ((1ull << i) - 1ull);
        live = __ballot(alive) & ~below;
      }
      if (inr && ((kept >> lane) & 1ull)) keptF[l*1024 + rnk] = 1;
      if (lane == 0) Kw[l*16 + c] = kept;   // in-wave DS ordering suffices
    }
  }
  __syncthreads();
  // --- compact kept per level into sorted LDS runs (ascending key) ---
  if (wid < 5){
    int l = wid, g = img*5 + l;
    int cnt = 0;
    for (int base = 0; base < 1024; base += 64){
      int r = base + lane;
      bool kp = keptF[l*1024 + r] != 0;
      u64 mask = __ballot(kp);
      int before = __popcll(mask & ((1ull << lane) - 1ull));
      if (kp) runs[l*1024 + cnt + before] = okeyL[g*1024 + r];
      cnt += __popcll(mask);
    }
    if (lane == 0) cl[l] = cnt;
  }
  __syncthreads();
  // --- defaults ---
  for (int t = tid; t < POST; t += 1024){
    out[img*POST*4 + t*4 + 0] = 0.0f;
    out[img*POST*4 + t*4 + 1] = 0.0f;
    out[img*POST*4 + t*4 + 2] = 0.0f;
    out[img*POST*4 + t*4 + 3] = 0.0f;
    out[2*POST*4 + img*POST + t] = -1.0f;
  }
  __syncthreads();
  // --- scatter: global rank = own index + sum of lower_bounds in other runs ---
  for (int idx = tid; idx < 5*1024; idx += 1024){
    int l = idx >> 10, i = idx & 1023;
    if (i < cl[l]){
      u64 key = runs[l*1024 + i];
      int rank = i;
      #pragma unroll
      for (int l2 = 0; l2 < 5; l2++)
        if (l2 != l) rank += lbound(runs + l2*1024, cl[l2], key);
      if (rank < POST){
        int pos = (int)(key & 0xFFFFFFFFull);
        int lvl = pos / 1000, r = pos - lvl*1000;
        int gg = img*5 + lvl;
        float4 bo = boxL[gg*1024 + r];
        float sc = scoreL[gg*1024 + r];
        out[img*POST*4 + rank*4 + 0] = bo.x;
        out[img*POST*4 + rank*4 + 1] = bo.y;
        out[img*POST*4 + rank*4 + 2] = bo.z;
        out[img*POST*4 + rank*4 + 3] = bo.w;
        out[2*POST*4 + img*POST + rank] = sc;
      }
    }
  }
}

extern "C" void kernel_launch(void* const* d_in, const int* in_sizes, int n_in,
                              void* d_out, int out_size, void* d_ws, size_t ws_size,
                              hipStream_t stream){
  (void)in_sizes; (void)n_in; (void)out_size; (void)ws_size;
  const float*  obj     = (const float*)d_in[0];
  const float4* deltas  = (const float4*)d_in[1];
  const float4* anchors = (const float4*)d_in[2];
  float* out = (float*)d_out;
  char* ws = (char*)d_ws;
  int* hist    = (int*)(ws + 0);           // 10*4096 int   -> 163840
  float4* boxL = (float4*)(ws + 163840);   // 10*1024 f4    -> 327680
  float* scoreL= (float*)(ws + 327680);    // 10*1024 f32   -> 368640
  u64* okeyL   = (u64*)(ws + 368640);      // 10*1024 u64   -> 450560
  float4* nbox = (float4*)(ws + 450560);   // 10*1024 f4    -> 614400
  int* nrank   = (int*)(ws + 614400);      // 10*1024 int   -> 655360
  int* ncnt    = (int*)(ws + 655360);      // 10 int (pad)  -> 655616
  u64* maskT   = (u64*)(ws + 655616);      // 10*1024*16 u64 -> 1966336

  hipMemsetAsync(hist, 0, 10*4096*sizeof(int), stream);
  {
    dim3 gh(10, 16);
    k_hist<<<gh, 256, 0, stream>>>(obj, hist);
  }
  k_sel  <<<10, 1024, 0, stream>>>(obj, deltas, anchors, hist, boxL, scoreL, okeyL, nbox, nrank, ncnt);
  {
    dim3 gm(10, 16, 16);
    k_mask<<<gm, 64, 0, stream>>>(nbox, ncnt, maskT);
  }
  k_scanmerge<<<2, 1024, 0, stream>>>(maskT, ncnt, nrank, okeyL, boxL, scoreL, out);
}

// Round 7
// 234.507 us; speedup vs baseline: 1.0777x; 1.0777x over previous
//
#include <hip/hip_runtime.h>

typedef unsigned long long u64;
typedef unsigned int u32;

#define R_TOT 159882
#define POST 1000
#define IMG_SZ 800.0f
#define NMS_TH 0.7f
#define BBOX_CLIP 4.135166556742356f
#define LCAP 2048

__device__ __forceinline__ float fadd_(float a, float b){ return __fadd_rn(a,b); }
__device__ __forceinline__ float fsub_(float a, float b){ return __fsub_rn(a,b); }
__device__ __forceinline__ float fmul_(float a, float b){ return __fmul_rn(a,b); }

__device__ __forceinline__ int lvl_len(int l){ const int L[5]={120000,30000,7500,1875,507}; return L[l]; }
__device__ __forceinline__ int lvl_off(int l){ const int L[5]={0,120000,150000,157500,159375}; return L[l]; }
__device__ __forceinline__ int lvl_k(int l){ const int L[5]={1000,1000,1000,1000,507}; return L[l]; }

__device__ __forceinline__ u32 mono_(u32 u){ return (u & 0x80000000u) ? ~u : (u | 0x80000000u); }

__device__ __forceinline__ u64 readlane64(u64 v, int i){
  u32 lo = (u32)__builtin_amdgcn_readlane((int)(u32)v, i);
  u32 hi = (u32)__builtin_amdgcn_readlane((int)(u32)(v >> 32), i);
  return ((u64)hi << 32) | (u64)lo;
}

// ---------- 1. 12-bit histogram per (img,lvl): LDS-private, merged once ----------
__global__ __launch_bounds__(256) void k_hist(const float* __restrict__ obj, int* hist){
  int g = blockIdx.x, sl = blockIdx.y;
  int img = g/5, lvl = g%5;
  int n = lvl_len(lvl), s0 = lvl_off(lvl);
  __shared__ int lh[4096];
  int tid = threadIdx.x;
  for (int i = tid; i < 4096; i += 256) lh[i] = 0;
  __syncthreads();
  int lo = (int)((long long)n * sl / 16), hiS = (int)((long long)n * (sl+1) / 16);
  const float* p = obj + img*R_TOT + s0;
  #pragma unroll 4
  for (int e = lo + tid; e < hiS; e += 256){
    u32 mu = mono_(__float_as_uint(p[e]));
    atomicAdd(&lh[(~mu) >> 20], 1);
  }
  __syncthreads();
  for (int i = tid; i < 4096; i += 256)
    if (lh[i]) atomicAdd(&hist[g*4096 + i], lh[i]);
}

// ---------- 2. fused: pick bin + gather + rank-resolve + sort + decode + prep ----------
__global__ __launch_bounds__(1024) void k_sel(const float* __restrict__ obj,
                                              const float4* __restrict__ deltas,
                                              const float4* __restrict__ anchors,
                                              const int* __restrict__ hist,
                                              float4* boxL, float* scoreL, u64* okeyL,
                                              float4* nbox, int* nrank, int* ncnt){
  int g = blockIdx.x, img = g/5, lvl = g%5;
  int s0 = lvl_off(lvl), n = lvl_len(lvl), k = lvl_k(lvl);
  const float* p = obj + img*R_TOT + s0;
  __shared__ u64 Lbuf[LCAP];
  __shared__ u64 mainL[1024];
  __shared__ float4 lbox[1024];
  __shared__ unsigned char lval[1024];
  __shared__ int wsum[16];
  __shared__ int h16[16];
  __shared__ int sh_b, sh_rem, sh_nb, sh_c2, sh_sc;
  __shared__ u64 sh_thr;
  int tid = threadIdx.x, lane = tid & 63, wid = tid >> 6;
  // --- pick k-th bin from global hist ---
  const int* hg = hist + g*4096;
  int hh[4] = {hg[4*tid], hg[4*tid+1], hg[4*tid+2], hg[4*tid+3]};
  int part = hh[0] + hh[1] + hh[2] + hh[3];
  int x = part;
  for (int d = 1; d < 64; d <<= 1){ int y = __shfl_up(x, d); if (lane >= d) x += y; }
  if (lane == 63) wsum[wid] = x;
  if (tid == 0){ sh_nb = 0; sh_c2 = 0; sh_sc = 0; }
  mainL[tid] = ~0ull;
  __syncthreads();
  int add = 0;
  for (int w = 0; w < wid; w++) add += wsum[w];
  int incl = x + add, excl = incl - part;
  if (excl < k && k <= incl){
    int cum = excl;
    #pragma unroll
    for (int q = 0; q < 4; q++){
      if (cum + hh[q] >= k){ sh_b = 4*tid + q; sh_rem = k - cum; break; }
      cum += hh[q];
    }
  }
  __syncthreads();
  int bs = sh_b, rem = sh_rem;
  // --- single collect scan: bin<b* -> mainL, bin==b* -> Lbuf ---
  #pragma unroll 8
  for (int e = tid; e < n; e += 1024){
    u32 mu = mono_(__float_as_uint(p[e]));
    u64 key56 = (((u64)(~mu)) << 24) | (u32)(s0 + e);
    int bin = (int)(key56 >> 44);
    if (bin < bs){ int pos = atomicAdd(&sh_nb, 1); mainL[pos] = key56; }
    else if (bin == bs){ int pos = atomicAdd(&sh_c2, 1); if (pos < LCAP) Lbuf[pos] = key56; }
  }
  __syncthreads();
  int nb = sh_nb, c2 = sh_c2;
  if (c2 <= LCAP){
    // rank-select within the tie bin (uniform q -> LDS broadcast)
    for (int e = tid; e < c2; e += 1024){
      u64 kk = Lbuf[e];
      int rk = 0;
      for (int q = 0; q < c2; q++) rk += (Lbuf[q] < kk) ? 1 : 0;
      if (rk < rem){ int p2 = atomicAdd(&sh_sc, 1); mainL[nb + p2] = kk; }
    }
  } else {
    // fallback: 4-bit radix refine over global (never hit on bench data)
    if (tid == 0) sh_thr = ((u64)bs) << 44;
    __syncthreads();
    for (int shift = 40; shift >= 0; shift -= 4){
      if (tid < 16) h16[tid] = 0;
      __syncthreads();
      u64 pref = sh_thr;
      u64 himask = ~((1ull << (shift+4)) - 1ull);
      for (int e = tid; e < n; e += 1024){
        u32 mu = mono_(__float_as_uint(p[e]));
        u64 kk = (((u64)(~mu)) << 24) | (u32)(s0 + e);
        if ((kk & himask) == (pref & himask)) atomicAdd(&h16[(int)((kk >> shift) & 15)], 1);
      }
      __syncthreads();
      if (tid == 0){
        int r2 = sh_rem, cum = 0;
        for (int d = 0; d < 16; d++){
          int hb = h16[d];
          if (cum + hb >= r2){ sh_thr = pref | ((u64)d << shift); sh_rem = r2 - cum; break; }
          cum += hb;
        }
      }
      __syncthreads();
    }
    u64 thr = sh_thr;
    for (int e = tid; e < n; e += 1024){
      u32 mu = mono_(__float_as_uint(p[e]));
      u64 kk = (((u64)(~mu)) << 24) | (u32)(s0 + e);
      if ((int)(kk >> 44) == bs && kk <= thr){ int p2 = atomicAdd(&sh_sc, 1); mainL[nb + p2] = kk; }
    }
  }
  __syncthreads();
  // --- bitonic sort 1024 (55 stages) ---
  for (int k2 = 2; k2 <= 1024; k2 <<= 1){
    for (int j = k2 >> 1; j > 0; j >>= 1){
      __syncthreads();
      int i = tid, ixj = i ^ j;
      if (ixj > i){
        u64 a = mainL[i], b = mainL[ixj];
        bool up = (i & k2) == 0;
        if ((a > b) == up){ mainL[i] = b; mainL[ixj] = a; }
      }
    }
  }
  __syncthreads();
  // --- decode + clip + valid + sigmoid + okey ---
  int r = tid, t = g*1024 + r;
  if (r < k){
    int idx = (int)(mainL[r] & 0xFFFFFFu);
    float4 a = anchors[idx];
    float4 d = deltas[img*R_TOT + idx];
    float o = obj[img*R_TOT + idx];
    float wa = fsub_(a.z, a.x), ha = fsub_(a.w, a.y);
    float cxa = fadd_(a.x, fmul_(0.5f, wa)), cya = fadd_(a.y, fmul_(0.5f, ha));
    float dw = fminf(d.z, BBOX_CLIP), dh = fminf(d.w, BBOX_CLIP);
    float cx = fadd_(fmul_(d.x, wa), cxa), cy = fadd_(fmul_(d.y, ha), cya);
    float w  = fmul_(expf(dw), wa),        h  = fmul_(expf(dh), ha);
    float x1 = fsub_(cx, fmul_(0.5f, w)), y1 = fsub_(cy, fmul_(0.5f, h));
    float x2 = fadd_(cx, fmul_(0.5f, w)), y2 = fadd_(cy, fmul_(0.5f, h));
    x1 = fminf(fmaxf(x1, 0.0f), IMG_SZ); y1 = fminf(fmaxf(y1, 0.0f), IMG_SZ);
    x2 = fminf(fmaxf(x2, 0.0f), IMG_SZ); y2 = fminf(fmaxf(y2, 0.0f), IMG_SZ);
    bool valid = (fsub_(x2, x1) >= 1e-3f) && (fsub_(y2, y1) >= 1e-3f);
    float e = expf(-o);
    float sig = __fdiv_rn(1.0f, fadd_(1.0f, e));
    float s = valid ? sig : -1.0f;
    u32 sb = __float_as_uint(s);
    u32 ms = (sb & 0x80000000u) ? ~sb : (sb | 0x80000000u);
    float4 b4 = make_float4(x1, y1, x2, y2);
    boxL[t] = b4;
    scoreL[t] = sig;
    okeyL[t] = (((u64)(~ms)) << 32) | (u32)(lvl*1000 + r);
    lbox[r] = b4;
    lval[r] = valid ? 1 : 0;
  } else {
    lval[r] = 0;
  }
  __syncthreads();
  // --- valid-compaction (wave 0) with 801*lvl offset ---
  if (tid < 64){
    int cnt = 0;
    float off = (float)lvl * 801.0f;
    for (int base = 0; base < k; base += 64){
      int r2 = base + lane;
      bool v = (r2 < k) && lval[r2];
      float4 b = lbox[r2 < k ? r2 : 0];
      u64 mask = __ballot(v);
      int before = __popcll(mask & ((1ull << lane) - 1ull));
      if (v){
        int pos = cnt + before;
        nbox[g*1024 + pos] = make_float4(fadd_(b.x,off), fadd_(b.y,off), fadd_(b.z,off), fadd_(b.w,off));
        nrank[g*1024 + pos] = r2;
      }
      cnt += __popcll(mask);
    }
    if (lane == 0) ncnt[g] = cnt;
  }
}

// ---------- 3. transposed IoU bitmask + forward diagonal words ----------
__global__ __launch_bounds__(64) void k_mask(const float4* __restrict__ nbox,
                                             const int* __restrict__ ncnt,
                                             u64* maskT, u64* diagF){
  int g = blockIdx.x, tr = blockIdx.y, tw = blockIdx.z;
  if (tw > tr) return;
  int m = ncnt[g];
  if (tr*64 >= m) return;
  __shared__ float4 shb[64];
  int lane = threadIdx.x;
  if (tw*64 + lane < m) shb[lane] = nbox[g*1024 + tw*64 + lane];
  __syncthreads();
  int j = tr*64 + lane;
  if (j >= m) return;
  float4 a = nbox[g*1024 + j];
  float areaA = fmul_(fsub_(a.z,a.x), fsub_(a.w,a.y));
  int imax = m - tw*64; if (imax > 64) imax = 64;
  if (tw == tr){
    // diagonal tile: bitsT (suppressors with ii<lane) + bitsF (whom lane suppresses, ii>lane)
    u64 bitsT = 0, bitsF = 0;
    for (int ii = 0; ii < imax; ii++){
      if (ii == lane) continue;
      float4 b = shb[ii];
      float ltx = fmaxf(a.x, b.x), lty = fmaxf(a.y, b.y);
      float rbx = fminf(a.z, b.z), rby = fminf(a.w, b.w);
      float wx = fmaxf(fsub_(rbx, ltx), 0.0f), wy = fmaxf(fsub_(rby, lty), 0.0f);
      float inter = fmul_(wx, wy);
      float areaB = fmul_(fsub_(b.z,b.x), fsub_(b.w,b.y));
      float den = fadd_(fsub_(fadd_(areaA, areaB), inter), 1e-9f);
      if (__fdiv_rn(inter, den) > NMS_TH){
        if (ii < lane) bitsT |= (1ull << ii);   // symmetric IoU: identical value both roles
        else           bitsF |= (1ull << ii);
      }
    }
    maskT[(size_t)(g*1024 + j)*16 + tw] = bitsT;
    diagF[g*1024 + j] = bitsF;
  } else {
    u64 bits = 0;
    for (int ii = 0; ii < imax; ii++){
      float4 b = shb[ii];
      float ltx = fmaxf(a.x, b.x), lty = fmaxf(a.y, b.y);
      float rbx = fminf(a.z, b.z), rby = fminf(a.w, b.w);
      float wx = fmaxf(fsub_(rbx, ltx), 0.0f), wy = fmaxf(fsub_(rby, lty), 0.0f);
      float inter = fmul_(wx, wy);
      float areaB = fmul_(fsub_(b.z,b.x), fsub_(b.w,b.y));
      float den = fadd_(fsub_(fadd_(areaA, areaB), inter), 1e-9f);
      if (__fdiv_rn(inter, den) > NMS_TH) bits |= (1ull << ii);
    }
    maskT[(size_t)(g*1024 + j)*16 + tw] = bits;
  }
}

__device__ __forceinline__ int lbound(const u64* a, int n, u64 key){
  int lo = 0, hi = n;
  while (lo < hi){ int mid = (lo + hi) >> 1; if (a[mid] < key) lo = mid + 1; else hi = mid; }
  return lo;
}

// ---------- 4. fused greedy scan (scalar ffs chain) + 5-way merge by rank + output ----------
__global__ __launch_bounds__(1024) void k_scanmerge(const u64* __restrict__ maskT,
                                                    const u64* __restrict__ diagF,
                                                    const int* __restrict__ ncnt,
                                                    const int* __restrict__ nrank,
                                                    const u64* __restrict__ okeyL,
                                                    const float4* __restrict__ boxL,
                                                    const float* __restrict__ scoreL,
                                                    float* out){
  int img = blockIdx.x, tid = threadIdx.x, lane = tid & 63, wid = tid >> 6;
  __shared__ unsigned char keptF[5*1024];
  __shared__ u64 runs[5*1024];
  __shared__ u64 Kw[5*16];
  __shared__ int cl[5];
  for (int i = tid; i < 5*1024; i += 1024) keptF[i] = 0;
  if (tid < 80) Kw[tid] = 0;
  if (tid < 5) cl[tid] = 0;
  __syncthreads();
  // --- per-level greedy scan, one wave each ---
  // Serial chain is scalar: live (SGPR) updated by ANDing out the kept row's
  // forward word via v_readlane — no per-iteration ballot, no 64-bit VALU chain.
  if (wid < 5){
    int l = wid, g = img*5 + l;
    int m = ncnt[g];
    int nch = (m + 63) >> 6;
    for (int c = 0; c < nch; c++){
      int row = c*64 + lane;
      bool inr = row < m;
      const u64* rp = maskT + (size_t)(g*1024 + row)*16;
      u64 fwd = inr ? diagF[g*1024 + row] : 0;
      u64 supp = 0;
      #pragma unroll
      for (int q = 0; q < 15; q++){          // q < c <= 15; words >= c masked by Kw=0
        u64 v = (inr && q < c) ? rp[q] : 0;
        supp |= v & Kw[l*16 + q];
      }
      int rnk = inr ? nrank[g*1024 + row] : 0;
      u64 live = __ballot(inr && (supp == 0));
      u64 kept = 0;
      while (live){
        int i = __builtin_ctzll(live);
        kept |= (1ull << i);
        live &= ~(1ull << i);
        live &= ~readlane64(fwd, i);         // whom i suppresses in this chunk
      }
      if (inr && ((kept >> lane) & 1ull)) keptF[l*1024 + rnk] = 1;
      if (lane == 0) Kw[l*16 + c] = kept;    // in-wave DS ordering suffices
    }
  }
  __syncthreads();
  // --- compact kept per level into sorted LDS runs (ascending key) ---
  if (wid < 5){
    int l = wid, g = img*5 + l;
    int cnt = 0;
    for (int base = 0; base < 1024; base += 64){
      int r = base + lane;
      bool kp = keptF[l*1024 + r] != 0;
      u64 mask = __ballot(kp);
      int before = __popcll(mask & ((1ull << lane) - 1ull));
      if (kp) runs[l*1024 + cnt + before] = okeyL[g*1024 + r];
      cnt += __popcll(mask);
    }
    if (lane == 0) cl[l] = cnt;
  }
  __syncthreads();
  // --- defaults ---
  for (int t = tid; t < POST; t += 1024){
    out[img*POST*4 + t*4 + 0] = 0.0f;
    out[img*POST*4 + t*4 + 1] = 0.0f;
    out[img*POST*4 + t*4 + 2] = 0.0f;
    out[img*POST*4 + t*4 + 3] = 0.0f;
    out[2*POST*4 + img*POST + t] = -1.0f;
  }
  __syncthreads();
  // --- scatter: global rank = own index + sum of lower_bounds in other runs ---
  for (int idx = tid; idx < 5*1024; idx += 1024){
    int l = idx >> 10, i = idx & 1023;
    if (i < cl[l]){
      u64 key = runs[l*1024 + i];
      int rank = i;
      #pragma unroll
      for (int l2 = 0; l2 < 5; l2++)
        if (l2 != l) rank += lbound(runs + l2*1024, cl[l2], key);
      if (rank < POST){
        int pos = (int)(key & 0xFFFFFFFFull);
        int lvl = pos / 1000, r = pos - lvl*1000;
        int gg = img*5 + lvl;
        float4 bo = boxL[gg*1024 + r];
        float sc = scoreL[gg*1024 + r];
        out[img*POST*4 + rank*4 + 0] = bo.x;
        out[img*POST*4 + rank*4 + 1] = bo.y;
        out[img*POST*4 + rank*4 + 2] = bo.z;
        out[img*POST*4 + rank*4 + 3] = bo.w;
        out[2*POST*4 + img*POST + rank] = sc;
      }
    }
  }
}

extern "C" void kernel_launch(void* const* d_in, const int* in_sizes, int n_in,
                              void* d_out, int out_size, void* d_ws, size_t ws_size,
                              hipStream_t stream){
  (void)in_sizes; (void)n_in; (void)out_size; (void)ws_size;
  const float*  obj     = (const float*)d_in[0];
  const float4* deltas  = (const float4*)d_in[1];
  const float4* anchors = (const float4*)d_in[2];
  float* out = (float*)d_out;
  char* ws = (char*)d_ws;
  int* hist    = (int*)(ws + 0);           // 10*4096 int   -> 163840
  float4* boxL = (float4*)(ws + 163840);   // 10*1024 f4    -> 327680
  float* scoreL= (float*)(ws + 327680);    // 10*1024 f32   -> 368640
  u64* okeyL   = (u64*)(ws + 368640);      // 10*1024 u64   -> 450560
  float4* nbox = (float4*)(ws + 450560);   // 10*1024 f4    -> 614400
  int* nrank   = (int*)(ws + 614400);      // 10*1024 int   -> 655360
  int* ncnt    = (int*)(ws + 655360);      // 10 int (pad)  -> 655616
  u64* maskT   = (u64*)(ws + 655616);      // 10*1024*16 u64 -> 1966336
  u64* diagF   = (u64*)(ws + 1966336);     // 10*1024 u64   -> 2048256

  hipMemsetAsync(hist, 0, 10*4096*sizeof(int), stream);
  {
    dim3 gh(10, 16);
    k_hist<<<gh, 256, 0, stream>>>(obj, hist);
  }
  k_sel  <<<10, 1024, 0, stream>>>(obj, deltas, anchors, hist, boxL, scoreL, okeyL, nbox, nrank, ncnt);
  {
    dim3 gm(10, 16, 16);
    k_mask<<<gm, 64, 0, stream>>>(nbox, ncnt, maskT, diagF);
  }
  k_scanmerge<<<2, 1024, 0, stream>>>(maskT, diagF, ncnt, nrank, okeyL, boxL, scoreL, out);
}

// Round 8
// 229.520 us; speedup vs baseline: 1.1011x; 1.0217x over previous
//
#include <hip/hip_runtime.h>

typedef unsigned long long u64;
typedef unsigned int u32;

#define R_TOT 159882
#define POST 1000
#define IMG_SZ 800.0f
#define NMS_TH 0.7f
#define BBOX_CLIP 4.135166556742356f
#define LCAP 2048

__device__ __forceinline__ float fadd_(float a, float b){ return __fadd_rn(a,b); }
__device__ __forceinline__ float fsub_(float a, float b){ return __fsub_rn(a,b); }
__device__ __forceinline__ float fmul_(float a, float b){ return __fmul_rn(a,b); }

__device__ __forceinline__ int lvl_len(int l){ const int L[5]={120000,30000,7500,1875,507}; return L[l]; }
__device__ __forceinline__ int lvl_off(int l){ const int L[5]={0,120000,150000,157500,159375}; return L[l]; }
__device__ __forceinline__ int lvl_k(int l){ const int L[5]={1000,1000,1000,1000,507}; return L[l]; }

__device__ __forceinline__ u32 mono_(u32 u){ return (u & 0x80000000u) ? ~u : (u | 0x80000000u); }

__device__ __forceinline__ u64 readlane64(u64 v, int i){
  u32 lo = (u32)__builtin_amdgcn_readlane((int)(u32)v, i);
  u32 hi = (u32)__builtin_amdgcn_readlane((int)(u32)(v >> 32), i);
  return ((u64)hi << 32) | (u64)lo;
}

// ---------- 1. 12-bit histogram per (img,lvl): LDS-private, merged once ----------
__global__ __launch_bounds__(256) void k_hist(const float* __restrict__ obj, int* hist){
  int g = blockIdx.x, sl = blockIdx.y;
  int img = g/5, lvl = g%5;
  int n = lvl_len(lvl), s0 = lvl_off(lvl);
  __shared__ int lh[4096];
  int tid = threadIdx.x;
  for (int i = tid; i < 4096; i += 256) lh[i] = 0;
  __syncthreads();
  int lo = (int)((long long)n * sl / 16), hiS = (int)((long long)n * (sl+1) / 16);
  const float* p = obj + img*R_TOT + s0;
  #pragma unroll 4
  for (int e = lo + tid; e < hiS; e += 256){
    u32 mu = mono_(__float_as_uint(p[e]));
    atomicAdd(&lh[(~mu) >> 20], 1);
  }
  __syncthreads();
  for (int i = tid; i < 4096; i += 256)
    if (lh[i]) atomicAdd(&hist[g*4096 + i], lh[i]);
}

// ---------- 2. pick the k-th bin per (img,lvl); zero the collect counters ----------
__global__ __launch_bounds__(1024) void k_pick(const int* __restrict__ hist,
                                               int* bstarG, int* remG, int* cntg, int* cnt2){
  int g = blockIdx.x, lvl = g % 5, k = lvl_k(lvl);
  int tid = threadIdx.x, lane = tid & 63, wid = tid >> 6;
  __shared__ int wsum[16];
  const int* hg = hist + g*4096;
  int hh[4] = {hg[4*tid], hg[4*tid+1], hg[4*tid+2], hg[4*tid+3]};
  int part = hh[0] + hh[1] + hh[2] + hh[3];
  int x = part;
  for (int d = 1; d < 64; d <<= 1){ int y = __shfl_up(x, d); if (lane >= d) x += y; }
  if (lane == 63) wsum[wid] = x;
  __syncthreads();
  int add = 0;
  for (int w = 0; w < wid; w++) add += wsum[w];
  int incl = x + add, excl = incl - part;
  if (excl < k && k <= incl){
    int cum = excl;
    #pragma unroll
    for (int q = 0; q < 4; q++){
      if (cum + hh[q] >= k){ bstarG[g] = 4*tid + q; remG[g] = k - cum; break; }
      cum += hh[q];
    }
  }
  if (tid == 0){ cntg[g] = 0; cnt2[g] = 0; }
}

// ---------- 3. wide collect scan: bin<b* -> mainG, bin==b* -> LbufG ----------
__global__ __launch_bounds__(256) void k_collect(const float* __restrict__ obj,
                                                 const int* __restrict__ bstarG,
                                                 int* cntg, int* cnt2,
                                                 u64* mainG, u64* LbufG){
  int g = blockIdx.x, sl = blockIdx.y;
  int img = g/5, lvl = g%5;
  int n = lvl_len(lvl), s0 = lvl_off(lvl);
  int lo = (int)((long long)n * sl / 16), hiS = (int)((long long)n * (sl+1) / 16);
  const float* p = obj + img*R_TOT + s0;
  int bs = bstarG[g];
  #pragma unroll 8
  for (int e = lo + threadIdx.x; e < hiS; e += 256){
    u32 mu = mono_(__float_as_uint(p[e]));
    u64 key56 = (((u64)(~mu)) << 24) | (u32)(s0 + e);
    int bin = (int)(key56 >> 44);
    if (bin < bs){ int pos = atomicAdd(&cntg[g], 1); mainG[g*1024 + pos] = key56; }
    else if (bin == bs){ int pos = atomicAdd(&cnt2[g], 1); if (pos < LCAP) LbufG[g*LCAP + pos] = key56; }
  }
}

// ---------- 4. tie-resolve + sort + decode + prep (small LDS work per block) ----------
__global__ __launch_bounds__(1024) void k_seldecode(const float* __restrict__ obj,
                                                    const float4* __restrict__ deltas,
                                                    const float4* __restrict__ anchors,
                                                    const u64* __restrict__ mainG,
                                                    const u64* __restrict__ LbufG,
                                                    const int* __restrict__ cntg,
                                                    const int* __restrict__ cnt2,
                                                    const int* __restrict__ remG,
                                                    const int* __restrict__ bstarG,
                                                    float4* boxL, float* scoreL, u64* okeyL,
                                                    float4* nbox, int* nrank, int* ncnt){
  int g = blockIdx.x, img = g/5, lvl = g%5;
  int s0 = lvl_off(lvl), n = lvl_len(lvl), k = lvl_k(lvl);
  const float* p = obj + img*R_TOT + s0;
  __shared__ u64 Lbuf[LCAP];
  __shared__ u64 mainL[1024];
  __shared__ float4 lbox[1024];
  __shared__ unsigned char lval[1024];
  __shared__ int h16[16];
  __shared__ int sh_sc, sh_rem;
  __shared__ u64 sh_thr;
  int tid = threadIdx.x, lane = tid & 63;
  int nb = cntg[g];
  int c2 = cnt2[g];
  int rem = remG[g];
  int bs = bstarG[g];
  mainL[tid] = (tid < nb) ? mainG[g*1024 + tid] : ~0ull;
  if (tid == 0){ sh_sc = 0; sh_rem = rem; }
  int c2c = c2 < LCAP ? c2 : LCAP;
  for (int e = tid; e < c2c; e += 1024) Lbuf[e] = LbufG[g*LCAP + e];
  __syncthreads();
  if (c2 <= LCAP){
    // rank-select within the tie bin (order-independent)
    for (int e = tid; e < c2; e += 1024){
      u64 kk = Lbuf[e];
      int rk = 0;
      for (int q = 0; q < c2; q++) rk += (Lbuf[q] < kk) ? 1 : 0;
      if (rk < rem){ int p2 = atomicAdd(&sh_sc, 1); mainL[nb + p2] = kk; }
    }
  } else {
    // fallback: 4-bit radix refine over global (never hit on bench data)
    if (tid == 0) sh_thr = ((u64)bs) << 44;
    __syncthreads();
    for (int shift = 40; shift >= 0; shift -= 4){
      if (tid < 16) h16[tid] = 0;
      __syncthreads();
      u64 pref = sh_thr;
      u64 himask = ~((1ull << (shift+4)) - 1ull);
      for (int e = tid; e < n; e += 1024){
        u32 mu = mono_(__float_as_uint(p[e]));
        u64 kk = (((u64)(~mu)) << 24) | (u32)(s0 + e);
        if ((kk & himask) == (pref & himask)) atomicAdd(&h16[(int)((kk >> shift) & 15)], 1);
      }
      __syncthreads();
      if (tid == 0){
        int r2 = sh_rem, cum = 0;
        for (int d = 0; d < 16; d++){
          int hb = h16[d];
          if (cum + hb >= r2){ sh_thr = pref | ((u64)d << shift); sh_rem = r2 - cum; break; }
          cum += hb;
        }
      }
      __syncthreads();
    }
    u64 thr = sh_thr;
    for (int e = tid; e < n; e += 1024){
      u32 mu = mono_(__float_as_uint(p[e]));
      u64 kk = (((u64)(~mu)) << 24) | (u32)(s0 + e);
      if ((int)(kk >> 44) == bs && kk <= thr){ int p2 = atomicAdd(&sh_sc, 1); mainL[nb + p2] = kk; }
    }
  }
  __syncthreads();
  // --- bitonic sort 1024 ---
  for (int k2 = 2; k2 <= 1024; k2 <<= 1){
    for (int j = k2 >> 1; j > 0; j >>= 1){
      __syncthreads();
      int i = tid, ixj = i ^ j;
      if (ixj > i){
        u64 a = mainL[i], b = mainL[ixj];
        bool up = (i & k2) == 0;
        if ((a > b) == up){ mainL[i] = b; mainL[ixj] = a; }
      }
    }
  }
  __syncthreads();
  // --- decode + clip + valid + sigmoid + okey ---
  int r = tid, t = g*1024 + r;
  if (r < k){
    int idx = (int)(mainL[r] & 0xFFFFFFu);
    float4 a = anchors[idx];
    float4 d = deltas[img*R_TOT + idx];
    float o = obj[img*R_TOT + idx];
    float wa = fsub_(a.z, a.x), ha = fsub_(a.w, a.y);
    float cxa = fadd_(a.x, fmul_(0.5f, wa)), cya = fadd_(a.y, fmul_(0.5f, ha));
    float dw = fminf(d.z, BBOX_CLIP), dh = fminf(d.w, BBOX_CLIP);
    float cx = fadd_(fmul_(d.x, wa), cxa), cy = fadd_(fmul_(d.y, ha), cya);
    float w  = fmul_(expf(dw), wa),        h  = fmul_(expf(dh), ha);
    float x1 = fsub_(cx, fmul_(0.5f, w)), y1 = fsub_(cy, fmul_(0.5f, h));
    float x2 = fadd_(cx, fmul_(0.5f, w)), y2 = fadd_(cy, fmul_(0.5f, h));
    x1 = fminf(fmaxf(x1, 0.0f), IMG_SZ); y1 = fminf(fmaxf(y1, 0.0f), IMG_SZ);
    x2 = fminf(fmaxf(x2, 0.0f), IMG_SZ); y2 = fminf(fmaxf(y2, 0.0f), IMG_SZ);
    bool valid = (fsub_(x2, x1) >= 1e-3f) && (fsub_(y2, y1) >= 1e-3f);
    float e = expf(-o);
    float sig = __fdiv_rn(1.0f, fadd_(1.0f, e));
    float s = valid ? sig : -1.0f;
    u32 sb = __float_as_uint(s);
    u32 ms = (sb & 0x80000000u) ? ~sb : (sb | 0x80000000u);
    float4 b4 = make_float4(x1, y1, x2, y2);
    boxL[t] = b4;
    scoreL[t] = sig;
    okeyL[t] = (((u64)(~ms)) << 32) | (u32)(lvl*1000 + r);
    lbox[r] = b4;
    lval[r] = valid ? 1 : 0;
  } else {
    lval[r] = 0;
  }
  __syncthreads();
  // --- valid-compaction (wave 0) with 801*lvl offset ---
  if (tid < 64){
    int cnt = 0;
    float off = (float)lvl * 801.0f;
    for (int base = 0; base < k; base += 64){
      int r2 = base + lane;
      bool v = (r2 < k) && lval[r2];
      float4 b = lbox[r2 < k ? r2 : 0];
      u64 mask = __ballot(v);
      int before = __popcll(mask & ((1ull << lane) - 1ull));
      if (v){
        int pos = cnt + before;
        nbox[g*1024 + pos] = make_float4(fadd_(b.x,off), fadd_(b.y,off), fadd_(b.z,off), fadd_(b.w,off));
        nrank[g*1024 + pos] = r2;
      }
      cnt += __popcll(mask);
    }
    if (lane == 0) ncnt[g] = cnt;
  }
}

// ---------- 5. transposed IoU bitmask + forward diagonal words ----------
__global__ __launch_bounds__(64) void k_mask(const float4* __restrict__ nbox,
                                             const int* __restrict__ ncnt,
                                             u64* maskT, u64* diagF){
  int g = blockIdx.x, tr = blockIdx.y, tw = blockIdx.z;
  if (tw > tr) return;
  int m = ncnt[g];
  if (tr*64 >= m) return;
  __shared__ float4 shb[64];
  int lane = threadIdx.x;
  if (tw*64 + lane < m) shb[lane] = nbox[g*1024 + tw*64 + lane];
  __syncthreads();
  int j = tr*64 + lane;
  if (j >= m) return;
  float4 a = nbox[g*1024 + j];
  float areaA = fmul_(fsub_(a.z,a.x), fsub_(a.w,a.y));
  int imax = m - tw*64; if (imax > 64) imax = 64;
  if (tw == tr){
    u64 bitsT = 0, bitsF = 0;
    for (int ii = 0; ii < imax; ii++){
      if (ii == lane) continue;
      float4 b = shb[ii];
      float ltx = fmaxf(a.x, b.x), lty = fmaxf(a.y, b.y);
      float rbx = fminf(a.z, b.z), rby = fminf(a.w, b.w);
      float wx = fmaxf(fsub_(rbx, ltx), 0.0f), wy = fmaxf(fsub_(rby, lty), 0.0f);
      float inter = fmul_(wx, wy);
      float areaB = fmul_(fsub_(b.z,b.x), fsub_(b.w,b.y));
      float den = fadd_(fsub_(fadd_(areaA, areaB), inter), 1e-9f);
      if (__fdiv_rn(inter, den) > NMS_TH){
        if (ii < lane) bitsT |= (1ull << ii);   // symmetric IoU: identical value both roles
        else           bitsF |= (1ull << ii);
      }
    }
    maskT[(size_t)(g*1024 + j)*16 + tw] = bitsT;
    diagF[g*1024 + j] = bitsF;
  } else {
    u64 bits = 0;
    for (int ii = 0; ii < imax; ii++){
      float4 b = shb[ii];
      float ltx = fmaxf(a.x, b.x), lty = fmaxf(a.y, b.y);
      float rbx = fminf(a.z, b.z), rby = fminf(a.w, b.w);
      float wx = fmaxf(fsub_(rbx, ltx), 0.0f), wy = fmaxf(fsub_(rby, lty), 0.0f);
      float inter = fmul_(wx, wy);
      float areaB = fmul_(fsub_(b.z,b.x), fsub_(b.w,b.y));
      float den = fadd_(fsub_(fadd_(areaA, areaB), inter), 1e-9f);
      if (__fdiv_rn(inter, den) > NMS_TH) bits |= (1ull << ii);
    }
    maskT[(size_t)(g*1024 + j)*16 + tw] = bits;
  }
}

__device__ __forceinline__ int lbound(const u64* a, int n, u64 key){
  int lo = 0, hi = n;
  while (lo < hi){ int mid = (lo + hi) >> 1; if (a[mid] < key) lo = mid + 1; else hi = mid; }
  return lo;
}

// ---------- 6. fused greedy scan (scalar ffs chain) + 5-way merge by rank + output ----------
__global__ __launch_bounds__(1024) void k_scanmerge(const u64* __restrict__ maskT,
                                                    const u64* __restrict__ diagF,
                                                    const int* __restrict__ ncnt,
                                                    const int* __restrict__ nrank,
                                                    const u64* __restrict__ okeyL,
                                                    const float4* __restrict__ boxL,
                                                    const float* __restrict__ scoreL,
                                                    float* out){
  int img = blockIdx.x, tid = threadIdx.x, lane = tid & 63, wid = tid >> 6;
  __shared__ unsigned char keptF[5*1024];
  __shared__ u64 runs[5*1024];
  __shared__ u64 Kw[5*16];
  __shared__ int cl[5];
  for (int i = tid; i < 5*1024; i += 1024) keptF[i] = 0;
  if (tid < 80) Kw[tid] = 0;
  if (tid < 5) cl[tid] = 0;
  __syncthreads();
  if (wid < 5){
    int l = wid, g = img*5 + l;
    int m = ncnt[g];
    int nch = (m + 63) >> 6;
    for (int c = 0; c < nch; c++){
      int row = c*64 + lane;
      bool inr = row < m;
      const u64* rp = maskT + (size_t)(g*1024 + row)*16;
      u64 fwd = inr ? diagF[g*1024 + row] : 0;
      u64 supp = 0;
      #pragma unroll
      for (int q = 0; q < 15; q++){
        u64 v = (inr && q < c) ? rp[q] : 0;
        supp |= v & Kw[l*16 + q];
      }
      int rnk = inr ? nrank[g*1024 + row] : 0;
      u64 live = __ballot(inr && (supp == 0));
      u64 kept = 0;
      while (live){
        int i = __builtin_ctzll(live);
        kept |= (1ull << i);
        live &= ~(1ull << i);
        live &= ~readlane64(fwd, i);
      }
      if (inr && ((kept >> lane) & 1ull)) keptF[l*1024 + rnk] = 1;
      if (lane == 0) Kw[l*16 + c] = kept;
    }
  }
  __syncthreads();
  if (wid < 5){
    int l = wid, g = img*5 + l;
    int cnt = 0;
    for (int base = 0; base < 1024; base += 64){
      int r = base + lane;
      bool kp = keptF[l*1024 + r] != 0;
      u64 mask = __ballot(kp);
      int before = __popcll(mask & ((1ull << lane) - 1ull));
      if (kp) runs[l*1024 + cnt + before] = okeyL[g*1024 + r];
      cnt += __popcll(mask);
    }
    if (lane == 0) cl[l] = cnt;
  }
  __syncthreads();
  for (int t = tid; t < POST; t += 1024){
    out[img*POST*4 + t*4 + 0] = 0.0f;
    out[img*POST*4 + t*4 + 1] = 0.0f;
    out[img*POST*4 + t*4 + 2] = 0.0f;
    out[img*POST*4 + t*4 + 3] = 0.0f;
    out[2*POST*4 + img*POST + t] = -1.0f;
  }
  __syncthreads();
  for (int idx = tid; idx < 5*1024; idx += 1024){
    int l = idx >> 10, i = idx & 1023;
    if (i < cl[l]){
      u64 key = runs[l*1024 + i];
      int rank = i;
      #pragma unroll
      for (int l2 = 0; l2 < 5; l2++)
        if (l2 != l) rank += lbound(runs + l2*1024, cl[l2], key);
      if (rank < POST){
        int pos = (int)(key & 0xFFFFFFFFull);
        int lvl = pos / 1000, r = pos - lvl*1000;
        int gg = img*5 + lvl;
        float4 bo = boxL[gg*1024 + r];
        float sc = scoreL[gg*1024 + r];
        out[img*POST*4 + rank*4 + 0] = bo.x;
        out[img*POST*4 + rank*4 + 1] = bo.y;
        out[img*POST*4 + rank*4 + 2] = bo.z;
        out[img*POST*4 + rank*4 + 3] = bo.w;
        out[2*POST*4 + img*POST + rank] = sc;
      }
    }
  }
}

extern "C" void kernel_launch(void* const* d_in, const int* in_sizes, int n_in,
                              void* d_out, int out_size, void* d_ws, size_t ws_size,
                              hipStream_t stream){
  (void)in_sizes; (void)n_in; (void)out_size; (void)ws_size;
  const float*  obj     = (const float*)d_in[0];
  const float4* deltas  = (const float4*)d_in[1];
  const float4* anchors = (const float4*)d_in[2];
  float* out = (float*)d_out;
  char* ws = (char*)d_ws;
  int* hist    = (int*)(ws + 0);           // 10*4096 int   -> 163840
  int* bstarG  = (int*)(ws + 163840);      // 10 int        -> 164096
  int* remG    = (int*)(ws + 164096);      // 10 int        -> 164352
  int* cntg    = (int*)(ws + 164352);      // 10 int        -> 164608
  int* cnt2    = (int*)(ws + 164608);      // 10 int        -> 164864
  u64* mainG   = (u64*)(ws + 164864);      // 10*1024 u64   -> 246784
  u64* LbufG   = (u64*)(ws + 246784);      // 10*2048 u64   -> 410624
  float4* boxL = (float4*)(ws + 410624);   // 10*1024 f4    -> 574464
  float* scoreL= (float*)(ws + 574464);    // 10*1024 f32   -> 615424
  u64* okeyL   = (u64*)(ws + 615424);      // 10*1024 u64   -> 697344
  float4* nbox = (float4*)(ws + 697344);   // 10*1024 f4    -> 861184
  int* nrank   = (int*)(ws + 861184);      // 10*1024 int   -> 902144
  int* ncnt    = (int*)(ws + 902144);      // 10 int (pad)  -> 902400
  u64* maskT   = (u64*)(ws + 902400);      // 10*1024*16 u64 -> 2213120
  u64* diagF   = (u64*)(ws + 2213120);     // 10*1024 u64   -> 2295040

  hipMemsetAsync(hist, 0, 10*4096*sizeof(int), stream);
  {
    dim3 gh(10, 16);
    k_hist<<<gh, 256, 0, stream>>>(obj, hist);
  }
  k_pick<<<10, 1024, 0, stream>>>(hist, bstarG, remG, cntg, cnt2);
  {
    dim3 gc(10, 16);
    k_collect<<<gc, 256, 0, stream>>>(obj, bstarG, cntg, cnt2, mainG, LbufG);
  }
  k_seldecode<<<10, 1024, 0, stream>>>(obj, deltas, anchors, mainG, LbufG, cntg, cnt2,
                                       remG, bstarG, boxL, scoreL, okeyL, nbox, nrank, ncnt);
  {
    dim3 gm(10, 16, 16);
    k_mask<<<gm, 64, 0, stream>>>(nbox, ncnt, maskT, diagF);
  }
  k_scanmerge<<<2, 1024, 0, stream>>>(maskT, diagF, ncnt, nrank, okeyL, boxL, scoreL, out);
}

// Round 9
// 210.608 us; speedup vs baseline: 1.2000x; 1.0898x over previous
//
#include <hip/hip_runtime.h>

typedef unsigned long long u64;
typedef unsigned int u32;

#define R_TOT 159882
#define POST 1000
#define IMG_SZ 800.0f
#define NMS_TH 0.7f
#define BBOX_CLIP 4.135166556742356f
#define LCAP 2048
#define TRI_FULL 7680   // 64 * (0+1+...+15) u64 per level (packed lower triangle)
#define TRI_LDS  6720   // 64 * (0+1+...+14) u64 (chunks c<=14 staged in LDS)

__device__ __forceinline__ float fadd_(float a, float b){ return __fadd_rn(a,b); }
__device__ __forceinline__ float fsub_(float a, float b){ return __fsub_rn(a,b); }
__device__ __forceinline__ float fmul_(float a, float b){ return __fmul_rn(a,b); }

__device__ __forceinline__ int lvl_len(int l){ const int L[5]={120000,30000,7500,1875,507}; return L[l]; }
__device__ __forceinline__ int lvl_off(int l){ const int L[5]={0,120000,150000,157500,159375}; return L[l]; }
__device__ __forceinline__ int lvl_k(int l){ const int L[5]={1000,1000,1000,1000,507}; return L[l]; }

__device__ __forceinline__ u32 mono_(u32 u){ return (u & 0x80000000u) ? ~u : (u | 0x80000000u); }

__device__ __forceinline__ u64 readlane64(u64 v, int i){
  u32 lo = (u32)__builtin_amdgcn_readlane((int)(u32)v, i);
  u32 hi = (u32)__builtin_amdgcn_readlane((int)(u32)(v >> 32), i);
  return ((u64)hi << 32) | (u64)lo;
}

// ---------- 1. 12-bit histogram per (img,lvl): LDS-private, merged once ----------
__global__ __launch_bounds__(256) void k_hist(const float* __restrict__ obj, int* hist){
  int g = blockIdx.x, sl = blockIdx.y;
  int img = g/5, lvl = g%5;
  int n = lvl_len(lvl), s0 = lvl_off(lvl);
  __shared__ int lh[4096];
  int tid = threadIdx.x;
  for (int i = tid; i < 4096; i += 256) lh[i] = 0;
  __syncthreads();
  int lo = (int)((long long)n * sl / 16), hiS = (int)((long long)n * (sl+1) / 16);
  const float* p = obj + img*R_TOT + s0;
  #pragma unroll 4
  for (int e = lo + tid; e < hiS; e += 256){
    u32 mu = mono_(__float_as_uint(p[e]));
    atomicAdd(&lh[(~mu) >> 20], 1);
  }
  __syncthreads();
  for (int i = tid; i < 4096; i += 256)
    if (lh[i]) atomicAdd(&hist[g*4096 + i], lh[i]);
}

// ---------- 2. pick the k-th bin per (img,lvl); zero the collect counters ----------
__global__ __launch_bounds__(1024) void k_pick(const int* __restrict__ hist,
                                               int* bstarG, int* remG, int* cntg, int* cnt2){
  int g = blockIdx.x, lvl = g % 5, k = lvl_k(lvl);
  int tid = threadIdx.x, lane = tid & 63, wid = tid >> 6;
  __shared__ int wsum[16];
  const int* hg = hist + g*4096;
  int hh[4] = {hg[4*tid], hg[4*tid+1], hg[4*tid+2], hg[4*tid+3]};
  int part = hh[0] + hh[1] + hh[2] + hh[3];
  int x = part;
  for (int d = 1; d < 64; d <<= 1){ int y = __shfl_up(x, d); if (lane >= d) x += y; }
  if (lane == 63) wsum[wid] = x;
  __syncthreads();
  int add = 0;
  for (int w = 0; w < wid; w++) add += wsum[w];
  int incl = x + add, excl = incl - part;
  if (excl < k && k <= incl){
    int cum = excl;
    #pragma unroll
    for (int q = 0; q < 4; q++){
      if (cum + hh[q] >= k){ bstarG[g] = 4*tid + q; remG[g] = k - cum; break; }
      cum += hh[q];
    }
  }
  if (tid == 0){ cntg[g] = 0; cnt2[g] = 0; }
}

// ---------- 3. wide collect scan: bin<b* -> mainG, bin==b* -> LbufG ----------
__global__ __launch_bounds__(256) void k_collect(const float* __restrict__ obj,
                                                 const int* __restrict__ bstarG,
                                                 int* cntg, int* cnt2,
                                                 u64* mainG, u64* LbufG){
  int g = blockIdx.x, sl = blockIdx.y;
  int img = g/5, lvl = g%5;
  int n = lvl_len(lvl), s0 = lvl_off(lvl);
  int lo = (int)((long long)n * sl / 16), hiS = (int)((long long)n * (sl+1) / 16);
  const float* p = obj + img*R_TOT + s0;
  int bs = bstarG[g];
  #pragma unroll 8
  for (int e = lo + threadIdx.x; e < hiS; e += 256){
    u32 mu = mono_(__float_as_uint(p[e]));
    u64 key56 = (((u64)(~mu)) << 24) | (u32)(s0 + e);
    int bin = (int)(key56 >> 44);
    if (bin < bs){ int pos = atomicAdd(&cntg[g], 1); mainG[g*1024 + pos] = key56; }
    else if (bin == bs){ int pos = atomicAdd(&cnt2[g], 1); if (pos < LCAP) LbufG[g*LCAP + pos] = key56; }
  }
}

// ---------- 4. tie-resolve + sort + decode + prep (okey written in compacted order) ----------
__global__ __launch_bounds__(1024) void k_seldecode(const float* __restrict__ obj,
                                                    const float4* __restrict__ deltas,
                                                    const float4* __restrict__ anchors,
                                                    const u64* __restrict__ mainG,
                                                    const u64* __restrict__ LbufG,
                                                    const int* __restrict__ cntg,
                                                    const int* __restrict__ cnt2,
                                                    const int* __restrict__ remG,
                                                    const int* __restrict__ bstarG,
                                                    float4* boxL, float* scoreL,
                                                    float4* nbox, u64* okeyN, int* ncnt){
  int g = blockIdx.x, img = g/5, lvl = g%5;
  int s0 = lvl_off(lvl), n = lvl_len(lvl), k = lvl_k(lvl);
  const float* p = obj + img*R_TOT + s0;
  __shared__ u64 Lbuf[LCAP];
  __shared__ u64 mainL[1024];
  __shared__ float4 lbox[1024];
  __shared__ u64 lokey[1024];
  __shared__ unsigned char lval[1024];
  __shared__ int h16[16];
  __shared__ int sh_sc, sh_rem;
  __shared__ u64 sh_thr;
  int tid = threadIdx.x, lane = tid & 63;
  int nb = cntg[g];
  int c2 = cnt2[g];
  int rem = remG[g];
  int bs = bstarG[g];
  mainL[tid] = (tid < nb) ? mainG[g*1024 + tid] : ~0ull;
  if (tid == 0){ sh_sc = 0; sh_rem = rem; }
  int c2c = c2 < LCAP ? c2 : LCAP;
  for (int e = tid; e < c2c; e += 1024) Lbuf[e] = LbufG[g*LCAP + e];
  __syncthreads();
  if (c2 <= LCAP){
    for (int e = tid; e < c2; e += 1024){
      u64 kk = Lbuf[e];
      int rk = 0;
      for (int q = 0; q < c2; q++) rk += (Lbuf[q] < kk) ? 1 : 0;
      if (rk < rem){ int p2 = atomicAdd(&sh_sc, 1); mainL[nb + p2] = kk; }
    }
  } else {
    // fallback: 4-bit radix refine over global (never hit on bench data)
    if (tid == 0) sh_thr = ((u64)bs) << 44;
    __syncthreads();
    for (int shift = 40; shift >= 0; shift -= 4){
      if (tid < 16) h16[tid] = 0;
      __syncthreads();
      u64 pref = sh_thr;
      u64 himask = ~((1ull << (shift+4)) - 1ull);
      for (int e = tid; e < n; e += 1024){
        u32 mu = mono_(__float_as_uint(p[e]));
        u64 kk = (((u64)(~mu)) << 24) | (u32)(s0 + e);
        if ((kk & himask) == (pref & himask)) atomicAdd(&h16[(int)((kk >> shift) & 15)], 1);
      }
      __syncthreads();
      if (tid == 0){
        int r2 = sh_rem, cum = 0;
        for (int d = 0; d < 16; d++){
          int hb = h16[d];
          if (cum + hb >= r2){ sh_thr = pref | ((u64)d << shift); sh_rem = r2 - cum; break; }
          cum += hb;
        }
      }
      __syncthreads();
    }
    u64 thr = sh_thr;
    for (int e = tid; e < n; e += 1024){
      u32 mu = mono_(__float_as_uint(p[e]));
      u64 kk = (((u64)(~mu)) << 24) | (u32)(s0 + e);
      if ((int)(kk >> 44) == bs && kk <= thr){ int p2 = atomicAdd(&sh_sc, 1); mainL[nb + p2] = kk; }
    }
  }
  __syncthreads();
  // --- bitonic sort 1024 ---
  for (int k2 = 2; k2 <= 1024; k2 <<= 1){
    for (int j = k2 >> 1; j > 0; j >>= 1){
      __syncthreads();
      int i = tid, ixj = i ^ j;
      if (ixj > i){
        u64 a = mainL[i], b = mainL[ixj];
        bool up = (i & k2) == 0;
        if ((a > b) == up){ mainL[i] = b; mainL[ixj] = a; }
      }
    }
  }
  __syncthreads();
  // --- decode + clip + valid + sigmoid + okey ---
  int r = tid, t = g*1024 + r;
  if (r < k){
    int idx = (int)(mainL[r] & 0xFFFFFFu);
    float4 a = anchors[idx];
    float4 d = deltas[img*R_TOT + idx];
    float o = obj[img*R_TOT + idx];
    float wa = fsub_(a.z, a.x), ha = fsub_(a.w, a.y);
    float cxa = fadd_(a.x, fmul_(0.5f, wa)), cya = fadd_(a.y, fmul_(0.5f, ha));
    float dw = fminf(d.z, BBOX_CLIP), dh = fminf(d.w, BBOX_CLIP);
    float cx = fadd_(fmul_(d.x, wa), cxa), cy = fadd_(fmul_(d.y, ha), cya);
    float w  = fmul_(expf(dw), wa),        h  = fmul_(expf(dh), ha);
    float x1 = fsub_(cx, fmul_(0.5f, w)), y1 = fsub_(cy, fmul_(0.5f, h));
    float x2 = fadd_(cx, fmul_(0.5f, w)), y2 = fadd_(cy, fmul_(0.5f, h));
    x1 = fminf(fmaxf(x1, 0.0f), IMG_SZ); y1 = fminf(fmaxf(y1, 0.0f), IMG_SZ);
    x2 = fminf(fmaxf(x2, 0.0f), IMG_SZ); y2 = fminf(fmaxf(y2, 0.0f), IMG_SZ);
    bool valid = (fsub_(x2, x1) >= 1e-3f) && (fsub_(y2, y1) >= 1e-3f);
    float e = expf(-o);
    float sig = __fdiv_rn(1.0f, fadd_(1.0f, e));
    float s = valid ? sig : -1.0f;
    u32 sb = __float_as_uint(s);
    u32 ms = (sb & 0x80000000u) ? ~sb : (sb | 0x80000000u);
    float4 b4 = make_float4(x1, y1, x2, y2);
    boxL[t] = b4;
    scoreL[t] = sig;
    lokey[r] = (((u64)(~ms)) << 32) | (u32)(lvl*1000 + r);
    lbox[r] = b4;
    lval[r] = valid ? 1 : 0;
  } else {
    lval[r] = 0;
  }
  __syncthreads();
  // --- valid-compaction (wave 0): nbox (+801*lvl offset) and okey in compacted order ---
  if (tid < 64){
    int cnt = 0;
    float off = (float)lvl * 801.0f;
    for (int base = 0; base < k; base += 64){
      int r2 = base + lane;
      bool v = (r2 < k) && lval[r2];
      float4 b = lbox[r2 < k ? r2 : 0];
      u64 mask = __ballot(v);
      int before = __popcll(mask & ((1ull << lane) - 1ull));
      if (v){
        int pos = cnt + before;
        nbox[g*1024 + pos] = make_float4(fadd_(b.x,off), fadd_(b.y,off), fadd_(b.z,off), fadd_(b.w,off));
        okeyN[g*1024 + pos] = lokey[r2];
      }
      cnt += __popcll(mask);
    }
    if (lane == 0) ncnt[g] = cnt;
  }
}

// ---------- 5. IoU bitmask: packed column-major triangle + forward diagonal words ----------
__global__ __launch_bounds__(64) void k_mask(const float4* __restrict__ nbox,
                                             const int* __restrict__ ncnt,
                                             u64* LTG, u64* diagF){
  int g = blockIdx.x, tr = blockIdx.y, tw = blockIdx.z;
  if (tw > tr) return;
  int m = ncnt[g];
  if (tr*64 >= m) return;
  __shared__ float4 shb[64];
  int lane = threadIdx.x;
  if (tw*64 + lane < m) shb[lane] = nbox[g*1024 + tw*64 + lane];
  __syncthreads();
  int j = tr*64 + lane;
  if (j >= m) return;
  float4 a = nbox[g*1024 + j];
  float areaA = fmul_(fsub_(a.z,a.x), fsub_(a.w,a.y));
  int imax = m - tw*64; if (imax > 64) imax = 64;
  if (tw == tr){
    // diagonal: only forward word (whom lane suppresses, ii > lane)
    u64 bitsF = 0;
    for (int ii = lane+1; ii < imax; ii++){
      float4 b = shb[ii];
      float ltx = fmaxf(a.x, b.x), lty = fmaxf(a.y, b.y);
      float rbx = fminf(a.z, b.z), rby = fminf(a.w, b.w);
      float wx = fmaxf(fsub_(rbx, ltx), 0.0f), wy = fmaxf(fsub_(rby, lty), 0.0f);
      float inter = fmul_(wx, wy);
      float areaB = fmul_(fsub_(b.z,b.x), fsub_(b.w,b.y));
      float den = fadd_(fsub_(fadd_(areaA, areaB), inter), 1e-9f);
      if (__fdiv_rn(inter, den) > NMS_TH) bitsF |= (1ull << ii);
    }
    diagF[g*1024 + j] = bitsF;
  } else {
    u64 bits = 0;
    for (int ii = 0; ii < imax; ii++){
      float4 b = shb[ii];
      float ltx = fmaxf(a.x, b.x), lty = fmaxf(a.y, b.y);
      float rbx = fminf(a.z, b.z), rby = fminf(a.w, b.w);
      float wx = fmaxf(fsub_(rbx, ltx), 0.0f), wy = fmaxf(fsub_(rby, lty), 0.0f);
      float inter = fmul_(wx, wy);
      float areaB = fmul_(fsub_(b.z,b.x), fsub_(b.w,b.y));
      float den = fadd_(fsub_(fadd_(areaA, areaB), inter), 1e-9f);
      if (__fdiv_rn(inter, den) > NMS_TH) bits |= (1ull << ii);
    }
    // packed column-major: word tw of row (tr*64+lane) at [tri(tr) + tw*64 + lane]
    LTG[(size_t)g*TRI_FULL + ((tr*(tr-1))/2 + tw)*64 + lane] = bits;
  }
}

// ---------- 6. greedy scan from LDS-staged triangle; bulk fast-path chain ----------
__global__ __launch_bounds__(256) void k_scan(const u64* __restrict__ LTG,
                                              const u64* __restrict__ diagF,
                                              const int* __restrict__ ncnt,
                                              u64* keptW){
  __shared__ u64 LT[TRI_LDS];
  __shared__ u64 dFL[1024];
  __shared__ u64 KwS[16];
  int g = blockIdx.x, tid = threadIdx.x;
  int m = ncnt[g];
  for (int i = tid; i < TRI_LDS; i += 256) LT[i] = LTG[(size_t)g*TRI_FULL + i];
  for (int i = tid; i < 1024; i += 256) dFL[i] = diagF[g*1024 + i];
  if (tid < 16) KwS[tid] = 0;
  __syncthreads();
  if (tid >= 64) return;
  int lane = tid;
  int nch = (m + 63) >> 6;
  for (int c = 0; c < nch; c++){
    int row = c*64 + lane;
    bool inr = row < m;
    u64 supp = 0;
    if (c < 15){
      int tb = (c*(c-1))/2;
      for (int q = 0; q < c; q++) supp |= LT[(tb+q)*64 + lane] & KwS[q];
    } else {
      const u64* gp = LTG + (size_t)g*TRI_FULL + 105*64;
      #pragma unroll
      for (int q = 0; q < 15; q++) supp |= gp[q*64 + lane] & KwS[q];
    }
    u64 fwd = inr ? dFL[row] : 0;
    u64 live = __ballot(inr && (supp == 0));
    u64 fz = __ballot(fwd != 0);
    u64 kept = 0;
    while (live){
      if (!(live & fz)){ kept |= live; break; }   // no remaining live lane suppresses anyone
      int i = __builtin_ctzll(live);
      kept |= (1ull << i);
      live &= ~(1ull << i);
      live &= ~readlane64(fwd, i);
    }
    KwS[c] = kept;                // uniform value; in-wave DS ordering suffices
    if (lane == 0) keptW[g*16 + c] = kept;
  }
}

__device__ __forceinline__ int lbound(const u64* a, int n, u64 key){
  int lo = 0, hi = n;
  while (lo < hi){ int mid = (lo + hi) >> 1; if (a[mid] < key) lo = mid + 1; else hi = mid; }
  return lo;
}

// ---------- 7. merge: runs from keptW/okeyN, rank by binary search, scatter ----------
__global__ __launch_bounds__(1024) void k_merge(const u64* __restrict__ keptW,
                                                const u64* __restrict__ okeyN,
                                                const int* __restrict__ ncnt,
                                                const float4* __restrict__ boxL,
                                                const float* __restrict__ scoreL,
                                                float* out){
  int img = blockIdx.x, tid = threadIdx.x, lane = tid & 63, wid = tid >> 6;
  __shared__ u64 runs[5*1024];
  __shared__ int cl[5];
  if (tid < 5) cl[tid] = 0;
  __syncthreads();
  if (wid < 5){
    int l = wid, g = img*5 + l;
    int m = ncnt[g];
    int nch = (m + 63) >> 6;
    int cnt = 0;
    for (int c = 0; c < nch; c++){
      u64 w = keptW[g*16 + c];
      bool kp = (w >> lane) & 1ull;
      int before = __popcll(w & ((1ull << lane) - 1ull));
      if (kp) runs[l*1024 + cnt + before] = okeyN[g*1024 + c*64 + lane];
      cnt += __popcll(w);
    }
    if (lane == 0) cl[l] = cnt;
  }
  __syncthreads();
  for (int t = tid; t < POST; t += 1024){
    out[img*POST*4 + t*4 + 0] = 0.0f;
    out[img*POST*4 + t*4 + 1] = 0.0f;
    out[img*POST*4 + t*4 + 2] = 0.0f;
    out[img*POST*4 + t*4 + 3] = 0.0f;
    out[2*POST*4 + img*POST + t] = -1.0f;
  }
  __syncthreads();
  for (int idx = tid; idx < 5*1024; idx += 1024){
    int l = idx >> 10, i = idx & 1023;
    if (i < cl[l]){
      u64 key = runs[l*1024 + i];
      int rank = i;
      #pragma unroll
      for (int l2 = 0; l2 < 5; l2++)
        if (l2 != l) rank += lbound(runs + l2*1024, cl[l2], key);
      if (rank < POST){
        int pos = (int)(key & 0xFFFFFFFFull);
        int lvl = pos / 1000, r = pos - lvl*1000;
        int gg = img*5 + lvl;
        float4 bo = boxL[gg*1024 + r];
        float sc = scoreL[gg*1024 + r];
        out[img*POST*4 + rank*4 + 0] = bo.x;
        out[img*POST*4 + rank*4 + 1] = bo.y;
        out[img*POST*4 + rank*4 + 2] = bo.z;
        out[img*POST*4 + rank*4 + 3] = bo.w;
        out[2*POST*4 + img*POST + rank] = sc;
      }
    }
  }
}

extern "C" void kernel_launch(void* const* d_in, const int* in_sizes, int n_in,
                              void* d_out, int out_size, void* d_ws, size_t ws_size,
                              hipStream_t stream){
  (void)in_sizes; (void)n_in; (void)out_size; (void)ws_size;
  const float*  obj     = (const float*)d_in[0];
  const float4* deltas  = (const float4*)d_in[1];
  const float4* anchors = (const float4*)d_in[2];
  float* out = (float*)d_out;
  char* ws = (char*)d_ws;
  int* hist    = (int*)(ws + 0);           // 10*4096 int   -> 163840
  int* bstarG  = (int*)(ws + 163840);      //               -> 164096
  int* remG    = (int*)(ws + 164096);      //               -> 164352
  int* cntg    = (int*)(ws + 164352);      //               -> 164608
  int* cnt2    = (int*)(ws + 164608);      //               -> 164864
  u64* mainG   = (u64*)(ws + 164864);      // 10*1024 u64   -> 246784
  u64* LbufG   = (u64*)(ws + 246784);      // 10*2048 u64   -> 410624
  float4* boxL = (float4*)(ws + 410624);   // 10*1024 f4    -> 574464
  float* scoreL= (float*)(ws + 574464);    // 10*1024 f32   -> 615424
  u64* okeyN   = (u64*)(ws + 615424);      // 10*1024 u64   -> 697344
  float4* nbox = (float4*)(ws + 697344);   // 10*1024 f4    -> 861184
  int* ncnt    = (int*)(ws + 861184);      // 10 int (pad)  -> 861440
  u64* LTG     = (u64*)(ws + 861440);      // 10*7680 u64   -> 1475840
  u64* diagF   = (u64*)(ws + 1475840);     // 10*1024 u64   -> 1557760
  u64* keptW   = (u64*)(ws + 1557760);     // 10*16 u64     -> 1559040

  hipMemsetAsync(hist, 0, 10*4096*sizeof(int), stream);
  {
    dim3 gh(10, 16);
    k_hist<<<gh, 256, 0, stream>>>(obj, hist);
  }
  k_pick<<<10, 1024, 0, stream>>>(hist, bstarG, remG, cntg, cnt2);
  {
    dim3 gc(10, 16);
    k_collect<<<gc, 256, 0, stream>>>(obj, bstarG, cntg, cnt2, mainG, LbufG);
  }
  k_seldecode<<<10, 1024, 0, stream>>>(obj, deltas, anchors, mainG, LbufG, cntg, cnt2,
                                       remG, bstarG, boxL, scoreL, nbox, okeyN, ncnt);
  {
    dim3 gm(10, 16, 16);
    k_mask<<<gm, 64, 0, stream>>>(nbox, ncnt, LTG, diagF);
  }
  k_scan<<<10, 256, 0, stream>>>(LTG, diagF, ncnt, keptW);
  k_merge<<<2, 1024, 0, stream>>>(keptW, okeyN, ncnt, boxL, scoreL, out);
}